// Round 1
// baseline (5032.211 us; speedup 1.0000x reference)
//
#include <hip/hip_runtime.h>
#include <math.h>

// Problem constants
#define NBATCH 16
#define NMENT  128          // M
#define NM     2048         // B*M rows
#define LSEQ   32
#define SSEQ   512
#define DD     768
#define NHEAD  12
#define HDIM   64
#define DFF    3072
#define NLAYER 4
#define NENT   50000

// ---------------------------------------------------------------------------
// t[b,l] = dot(lhs[b,l,:], attn_w)   (one wave per (b,l))
// ---------------------------------------------------------------------------
__global__ __launch_bounds__(64) void tdot_kernel(const float* __restrict__ lhs,
                                                  const float* __restrict__ aw,
                                                  float* __restrict__ t) {
  const int bl = blockIdx.x;       // b*32 + l
  const int b = bl >> 5, l = bl & 31;
  const int lane = threadIdx.x;
  const float* row = lhs + ((size_t)b * SSEQ + l) * DD;
  float s = 0.f;
#pragma unroll
  for (int u = 0; u < DD / 64; ++u)
    s += row[lane + 64 * u] * aw[lane + 64 * u];
#pragma unroll
  for (int off = 32; off > 0; off >>= 1) s += __shfl_down(s, off);
  if (lane == 0) t[bl] = s;
}

// ---------------------------------------------------------------------------
// Mention pooling: X[bm, :] = sum_l softmax_l(valid*t)[l] * valid[l] * lhs[b,l,:]
// attn_b cancels in the softmax (uniform shift).
// ---------------------------------------------------------------------------
__global__ __launch_bounds__(256) void pool_kernel(const float* __restrict__ lhs,
                                                   const int* __restrict__ pos,
                                                   const int* __restrict__ msk,
                                                   const float* __restrict__ t,
                                                   float* __restrict__ X) {
  __shared__ float wgt[LSEQ];
  __shared__ int ok[LSEQ];
  const int bm = blockIdx.x;
  const int b = bm >> 7;
  const int tid = threadIdx.x;
  if (tid < LSEQ) ok[tid] = (pos[(size_t)bm * LSEQ + tid] != -1) ? 1 : 0;
  __syncthreads();
  if (tid == 0) {
    const int mk = (msk[bm] != 0) ? 1 : 0;
    int run = 1;
    float lg[LSEQ];
    int vld[LSEQ];
#pragma unroll
    for (int l = 0; l < LSEQ; ++l) {
      run &= ok[l];
      vld[l] = mk & run;
      lg[l] = vld[l] ? t[b * LSEQ + l] : 0.f;
    }
    float mx = lg[0];
#pragma unroll
    for (int l = 1; l < LSEQ; ++l) mx = fmaxf(mx, lg[l]);
    float s = 0.f;
#pragma unroll
    for (int l = 0; l < LSEQ; ++l) { lg[l] = expf(lg[l] - mx); s += lg[l]; }
    const float inv = 1.f / s;
#pragma unroll
    for (int l = 0; l < LSEQ; ++l) wgt[l] = vld[l] ? lg[l] * inv : 0.f;
  }
  __syncthreads();
#pragma unroll
  for (int u = 0; u < 3; ++u) {
    const int d = tid + 256 * u;
    float acc = 0.f;
#pragma unroll
    for (int l = 0; l < LSEQ; ++l)
      acc += wgt[l] * lhs[((size_t)b * SSEQ + l) * DD + d];
    X[(size_t)bm * DD + d] = acc;
  }
}

// ---------------------------------------------------------------------------
// Generic guarded GEMM: C[M,N] = A[M,K] * Bw[N,K]^T + bias, optional relu.
// Tile 128x128, BK=16, 256 threads, 8x8 per thread, k-major LDS staging.
// ---------------------------------------------------------------------------
__global__ __launch_bounds__(256) void gemm_bt(const float* __restrict__ A,
                                               const float* __restrict__ Bw,
                                               const float* __restrict__ bias,
                                               float* __restrict__ C,
                                               int M, int N, int K, int dorelu) {
  __shared__ float As[16][132];
  __shared__ float Bs[16][132];
  const int tid = threadIdx.x;
  const int rb = blockIdx.y * 128;
  const int cb = blockIdx.x * 128;
  const int tm = (tid >> 4) * 8;
  const int tn = (tid & 15) * 8;
  const int am = tid >> 1;        // 0..127: row (A) / col (B) being staged
  const int ak = (tid & 1) * 8;   // k-offset half

  float acc[8][8];
#pragma unroll
  for (int i = 0; i < 8; ++i)
#pragma unroll
    for (int j = 0; j < 8; ++j) acc[i][j] = 0.f;

  for (int kb = 0; kb < K; kb += 16) {
    {
      const int gr = rb + am;
#pragma unroll
      for (int u = 0; u < 2; ++u) {
        const int kk = ak + u * 4;
        const int gk = kb + kk;
        float4 v = make_float4(0.f, 0.f, 0.f, 0.f);
        if (gr < M && gk + 3 < K) {
          v = *(const float4*)(A + (size_t)gr * K + gk);
        } else if (gr < M) {
          float tv[4] = {0.f, 0.f, 0.f, 0.f};
#pragma unroll
          for (int j = 0; j < 4; ++j)
            if (gk + j < K) tv[j] = A[(size_t)gr * K + gk + j];
          v = make_float4(tv[0], tv[1], tv[2], tv[3]);
        }
        As[kk + 0][am] = v.x; As[kk + 1][am] = v.y;
        As[kk + 2][am] = v.z; As[kk + 3][am] = v.w;
      }
      const int gc = cb + am;
#pragma unroll
      for (int u = 0; u < 2; ++u) {
        const int kk = ak + u * 4;
        const int gk = kb + kk;
        float4 v = make_float4(0.f, 0.f, 0.f, 0.f);
        if (gc < N && gk + 3 < K) {
          v = *(const float4*)(Bw + (size_t)gc * K + gk);
        } else if (gc < N) {
          float tv[4] = {0.f, 0.f, 0.f, 0.f};
#pragma unroll
          for (int j = 0; j < 4; ++j)
            if (gk + j < K) tv[j] = Bw[(size_t)gc * K + gk + j];
          v = make_float4(tv[0], tv[1], tv[2], tv[3]);
        }
        Bs[kk + 0][am] = v.x; Bs[kk + 1][am] = v.y;
        Bs[kk + 2][am] = v.z; Bs[kk + 3][am] = v.w;
      }
    }
    __syncthreads();
#pragma unroll
    for (int k = 0; k < 16; ++k) {
      float a[8], bv[8];
      *(float4*)&a[0] = *(const float4*)&As[k][tm];
      *(float4*)&a[4] = *(const float4*)&As[k][tm + 4];
      *(float4*)&bv[0] = *(const float4*)&Bs[k][tn];
      *(float4*)&bv[4] = *(const float4*)&Bs[k][tn + 4];
#pragma unroll
      for (int i = 0; i < 8; ++i)
#pragma unroll
        for (int j = 0; j < 8; ++j)
          acc[i][j] = fmaf(a[i], bv[j], acc[i][j]);
    }
    __syncthreads();
  }

  // epilogue: bias + relu + guarded float4 stores
  float bb[8];
#pragma unroll
  for (int j = 0; j < 8; ++j) {
    const int col = cb + tn + j;
    bb[j] = (bias != nullptr && col < N) ? bias[col] : 0.f;
  }
#pragma unroll
  for (int i = 0; i < 8; ++i) {
    const int row = rb + tm + i;
    if (row >= M) continue;
    float* crow = C + (size_t)row * N;
#pragma unroll
    for (int j0 = 0; j0 < 8; j0 += 4) {
      const int col = cb + tn + j0;
      float vv[4];
#pragma unroll
      for (int j = 0; j < 4; ++j) {
        float v = acc[i][j0 + j] + bb[j0 + j];
        if (dorelu) v = fmaxf(v, 0.f);
        vv[j] = v;
      }
      if (col + 3 < N) {
        *(float4*)(crow + col) = make_float4(vv[0], vv[1], vv[2], vv[3]);
      } else {
#pragma unroll
        for (int j = 0; j < 4; ++j)
          if (col + j < N) crow[col + j] = vv[j];
      }
    }
  }
}

// ---------------------------------------------------------------------------
// Attention: one block per (b, h). M=128 queries, HD=64. S kept in LDS.
// qkv rows: [q(768) | k(768) | v(768)], head h uses dims h*64..h*64+63.
// ---------------------------------------------------------------------------
__global__ __launch_bounds__(256) void attn_kernel(const float* __restrict__ qkv,
                                                   float* __restrict__ ao) {
  __shared__ float smem[2 * 64 * 132 + 128 * 132];   // 135168 B <= 160 KiB
  float* Qs = smem;                  // [64][132]  k-major: Qs[d*132 + m]
  float* Ks = smem + 64 * 132;       // [64][132]
  float* Ps = smem + 2 * 64 * 132;   // [128][132] c-major: Ps[c*132 + r]
  float* Vs = smem;                  // alias Q/K region after S is built: [128][68]

  const int tid = threadIdx.x;
  const int b = blockIdx.x / NHEAD;
  const int h = blockIdx.x % NHEAD;
  const float* base = qkv + (size_t)b * NMENT * (3 * DD) + h * HDIM;

  // load Q, K (k-major)
#pragma unroll
  for (int it = 0; it < 8; ++it) {
    const int idx = tid + it * 256;      // 0..2047
    const int m = idx >> 4;
    const int d0 = (idx & 15) * 4;
    const float4 q = *(const float4*)(base + (size_t)m * (3 * DD) + d0);
    const float4 k = *(const float4*)(base + (size_t)m * (3 * DD) + DD + d0);
    Qs[(d0 + 0) * 132 + m] = q.x; Qs[(d0 + 1) * 132 + m] = q.y;
    Qs[(d0 + 2) * 132 + m] = q.z; Qs[(d0 + 3) * 132 + m] = q.w;
    Ks[(d0 + 0) * 132 + m] = k.x; Ks[(d0 + 1) * 132 + m] = k.y;
    Ks[(d0 + 2) * 132 + m] = k.z; Ks[(d0 + 3) * 132 + m] = k.w;
  }
  __syncthreads();

  // S = scale * Q K^T, stored c-major into Ps
  const int tm = (tid >> 4) * 8;
  const int tn = (tid & 15) * 8;
  {
    float acc[8][8];
#pragma unroll
    for (int i = 0; i < 8; ++i)
#pragma unroll
      for (int j = 0; j < 8; ++j) acc[i][j] = 0.f;
    for (int d = 0; d < HDIM; ++d) {
      float a[8], bv[8];
      *(float4*)&a[0] = *(const float4*)&Qs[d * 132 + tm];
      *(float4*)&a[4] = *(const float4*)&Qs[d * 132 + tm + 4];
      *(float4*)&bv[0] = *(const float4*)&Ks[d * 132 + tn];
      *(float4*)&bv[4] = *(const float4*)&Ks[d * 132 + tn + 4];
#pragma unroll
      for (int i = 0; i < 8; ++i)
#pragma unroll
        for (int j = 0; j < 8; ++j)
          acc[i][j] = fmaf(a[i], bv[j], acc[i][j]);
    }
    const float scale = 0.125f;   // 1/sqrt(64)
#pragma unroll
    for (int i = 0; i < 8; ++i)
#pragma unroll
      for (int j = 0; j < 8; ++j)
        Ps[(tn + j) * 132 + (tm + i)] = acc[i][j] * scale;
  }
  __syncthreads();   // everyone done with Qs/Ks and Ps fully written

  // load V into aliased region; softmax over rows of Ps (disjoint memory)
#pragma unroll
  for (int it = 0; it < 8; ++it) {
    const int idx = tid + it * 256;
    const int m = idx >> 4;
    const int d0 = (idx & 15) * 4;
    const float4 v = *(const float4*)(base + (size_t)m * (3 * DD) + 2 * DD + d0);
    *(float4*)&Vs[m * 68 + d0] = v;
  }
  if (tid < NMENT) {
    const int r = tid;
    float mx = -1e30f;
    for (int c = 0; c < NMENT; ++c) mx = fmaxf(mx, Ps[c * 132 + r]);
    float s = 0.f;
    for (int c = 0; c < NMENT; ++c) {
      const float e = expf(Ps[c * 132 + r] - mx);
      Ps[c * 132 + r] = e;
      s += e;
    }
    const float inv = 1.f / s;
    for (int c = 0; c < NMENT; ++c) Ps[c * 132 + r] *= inv;
  }
  __syncthreads();

  // O = P V : per thread 8 rows x 4 dims
  const int om = (tid >> 4) * 8;
  const int od = (tid & 15) * 4;
  float oacc[8][4];
#pragma unroll
  for (int i = 0; i < 8; ++i)
#pragma unroll
    for (int j = 0; j < 4; ++j) oacc[i][j] = 0.f;
  for (int c = 0; c < NMENT; ++c) {
    float p[8];
    *(float4*)&p[0] = *(const float4*)&Ps[c * 132 + om];
    *(float4*)&p[4] = *(const float4*)&Ps[c * 132 + om + 4];
    const float4 vv = *(const float4*)&Vs[c * 68 + od];
#pragma unroll
    for (int i = 0; i < 8; ++i) {
      oacc[i][0] = fmaf(p[i], vv.x, oacc[i][0]);
      oacc[i][1] = fmaf(p[i], vv.y, oacc[i][1]);
      oacc[i][2] = fmaf(p[i], vv.z, oacc[i][2]);
      oacc[i][3] = fmaf(p[i], vv.w, oacc[i][3]);
    }
  }
#pragma unroll
  for (int i = 0; i < 8; ++i) {
    *(float4*)(ao + (size_t)(b * NMENT + om + i) * DD + h * HDIM + od) =
        make_float4(oacc[i][0], oacc[i][1], oacc[i][2], oacc[i][3]);
  }
}

// ---------------------------------------------------------------------------
// out = LayerNorm(x + y) * w + b   (one block per row; in-place safe: each
// thread writes only elements it read)
// ---------------------------------------------------------------------------
__global__ __launch_bounds__(256) void ln_kernel(const float* __restrict__ x,
                                                 const float* __restrict__ y,
                                                 const float* __restrict__ w,
                                                 const float* __restrict__ bb,
                                                 float* __restrict__ o) {
  __shared__ float red1[4], red2[4];
  __shared__ float mshare, vshare;
  const int row = blockIdx.x;
  const int tid = threadIdx.x;
  const int wave = tid >> 6, lane = tid & 63;
  const float* xr = x + (size_t)row * DD;
  const float* yr = y + (size_t)row * DD;
  float v[3];
  float s = 0.f;
#pragma unroll
  for (int u = 0; u < 3; ++u) {
    v[u] = xr[tid + 256 * u] + yr[tid + 256 * u];
    s += v[u];
  }
#pragma unroll
  for (int off = 32; off > 0; off >>= 1) s += __shfl_down(s, off);
  if (lane == 0) red1[wave] = s;
  __syncthreads();
  if (tid == 0) mshare = (red1[0] + red1[1] + red1[2] + red1[3]) * (1.f / DD);
  __syncthreads();
  const float mean = mshare;
  float q = 0.f;
#pragma unroll
  for (int u = 0; u < 3; ++u) { const float d = v[u] - mean; q += d * d; }
#pragma unroll
  for (int off = 32; off > 0; off >>= 1) q += __shfl_down(q, off);
  if (lane == 0) red2[wave] = q;
  __syncthreads();
  if (tid == 0)
    vshare = rsqrtf((red2[0] + red2[1] + red2[2] + red2[3]) * (1.f / DD) + 1e-5f);
  __syncthreads();
  const float rstd = vshare;
  float* orow = o + (size_t)row * DD;
#pragma unroll
  for (int u = 0; u < 3; ++u) {
    const int d = tid + 256 * u;
    orow[d] = (v[u] - mean) * rstd * w[d] + bb[d];
  }
}

// ---------------------------------------------------------------------------
extern "C" void kernel_launch(void* const* d_in, const int* in_sizes, int n_in,
                              void* d_out, int out_size, void* d_ws, size_t ws_size,
                              hipStream_t stream) {
  const float* lhs    = (const float*)d_in[0];
  const int*   pos    = (const int*)d_in[1];
  const int*   msk    = (const int*)d_in[2];
  const float* attn_w = (const float*)d_in[3];
  // d_in[4] attn_b: uniform shift, cancels in softmax
  const float* qkv_w  = (const float*)d_in[5];
  const float* qkv_b  = (const float*)d_in[6];
  const float* out_w  = (const float*)d_in[7];
  const float* out_b  = (const float*)d_in[8];
  const float* ln1_w  = (const float*)d_in[9];
  const float* ln1_b  = (const float*)d_in[10];
  const float* ff1_w  = (const float*)d_in[11];
  const float* ff1_b  = (const float*)d_in[12];
  const float* ff2_w  = (const float*)d_in[13];
  const float* ff2_b  = (const float*)d_in[14];
  const float* ln2_w  = (const float*)d_in[15];
  const float* ln2_b  = (const float*)d_in[16];
  const float* cls_w1 = (const float*)d_in[17];
  const float* cls_w2 = (const float*)d_in[18];
  const float* cls_b2 = (const float*)d_in[19];
  float* out = (float*)d_out;
  float* ws  = (float*)d_ws;

  // workspace layout (floats); total ~9.44M floats (~37.8 MB)
  float* T   = ws;                               // 512
  float* X   = ws + 512;                         // NM*768
  float* B1  = X + (size_t)NM * DD;              // NM*3072 (qkv | ffh)
  float* QKV = B1;                               // NM*2304
  float* AO  = B1 + (size_t)NM * (3 * DD);       // NM*768 (tail of B1)
  float* B3  = B1 + (size_t)NM * DFF;            // NM*768
  float* Hb  = B1;                               // NM*100 (reuse after layers)

  auto gemm = [&](const float* A, const float* Bw, const float* bias, float* C,
                  int M, int N, int K, int relu) {
    dim3 grid((N + 127) / 128, (M + 127) / 128);
    gemm_bt<<<grid, 256, 0, stream>>>(A, Bw, bias, C, M, N, K, relu);
  };

  tdot_kernel<<<NBATCH * LSEQ, 64, 0, stream>>>(lhs, attn_w, T);
  pool_kernel<<<NM, 256, 0, stream>>>(lhs, pos, msk, T, X);

  for (int i = 0; i < NLAYER; ++i) {
    gemm(X, qkv_w + (size_t)i * 3 * DD * DD, qkv_b + (size_t)i * 3 * DD, QKV,
         NM, 3 * DD, DD, 0);
    attn_kernel<<<NBATCH * NHEAD, 256, 0, stream>>>(QKV, AO);
    gemm(AO, out_w + (size_t)i * DD * DD, out_b + (size_t)i * DD, B3,
         NM, DD, DD, 0);
    ln_kernel<<<NM, 256, 0, stream>>>(X, B3, ln1_w + (size_t)i * DD,
                                      ln1_b + (size_t)i * DD, X);
    gemm(X, ff1_w + (size_t)i * DFF * DD, ff1_b + (size_t)i * DFF, B1,
         NM, DFF, DD, 1);
    gemm(B1, ff2_w + (size_t)i * DD * DFF, ff2_b + (size_t)i * DD, B3,
         NM, DD, DFF, 0);
    ln_kernel<<<NM, 256, 0, stream>>>(X, B3, ln2_w + (size_t)i * DD,
                                      ln2_b + (size_t)i * DD, X);
  }

  gemm(X, cls_w1, nullptr, Hb, NM, 100, DD, 0);
  gemm(Hb, cls_w2, cls_b2, out, NM, NENT, 100, 0);
}

// Round 2
// 1344.848 us; speedup vs baseline: 3.7418x; 3.7418x over previous
//
#include <hip/hip_runtime.h>
#include <math.h>

// Problem constants
#define NBATCH 16
#define NMENT  128          // M
#define NM     2048         // B*M rows
#define LSEQ   32
#define SSEQ   512
#define DD     768
#define NHEAD  12
#define HDIM   64
#define DFF    3072
#define NLAYER 4
#define NENT   50000

typedef __bf16 bf16;
typedef __attribute__((__ext_vector_type__(4))) float f32x4;
typedef __attribute__((__ext_vector_type__(8))) bf16 bf16x8;
typedef __attribute__((__ext_vector_type__(4))) bf16 bf16x4;

// ---------------------------------------------------------------------------
// async global->LDS, 16B per lane (dest = wave-uniform base + lane*16)
// ---------------------------------------------------------------------------
__device__ __forceinline__ void gl2lds16(const bf16* g, bf16* l) {
  __builtin_amdgcn_global_load_lds(
      (const __attribute__((address_space(1))) void*)g,
      (__attribute__((address_space(3))) void*)l, 16, 0, 0);
}

// ---------------------------------------------------------------------------
// fp32 -> bf16 flat convert (n4 = n/4 float4 chunks)
// ---------------------------------------------------------------------------
__global__ __launch_bounds__(256) void conv_bf16(const float* __restrict__ s,
                                                 bf16* __restrict__ d, int n4) {
  const int i = blockIdx.x * 256 + threadIdx.x;
  if (i >= n4) return;
  const float4 v = ((const float4*)s)[i];
  bf16x4 o;
  o.x = (bf16)v.x; o.y = (bf16)v.y; o.z = (bf16)v.z; o.w = (bf16)v.w;
  ((bf16x4*)d)[i] = o;
}

// fp32 [srows][scols] -> bf16 [drows][dcols] zero-padded
__global__ __launch_bounds__(256) void conv_pad(const float* __restrict__ s,
                                                bf16* __restrict__ d,
                                                int srows, int scols, int dcols,
                                                int total) {
  const int i = blockIdx.x * 256 + threadIdx.x;
  if (i >= total) return;
  const int r = i / dcols, c = i - r * dcols;
  const float v = (r < srows && c < scols) ? s[(size_t)r * scols + c] : 0.f;
  d[i] = (bf16)v;
}

// ---------------------------------------------------------------------------
// t[b,l] = dot(lhs[b,l,:], attn_w)
// ---------------------------------------------------------------------------
__global__ __launch_bounds__(64) void tdot_kernel(const float* __restrict__ lhs,
                                                  const float* __restrict__ aw,
                                                  float* __restrict__ t) {
  const int bl = blockIdx.x;
  const int b = bl >> 5, l = bl & 31;
  const int lane = threadIdx.x;
  const float* row = lhs + ((size_t)b * SSEQ + l) * DD;
  float s = 0.f;
#pragma unroll
  for (int u = 0; u < DD / 64; ++u)
    s += row[lane + 64 * u] * aw[lane + 64 * u];
#pragma unroll
  for (int off = 32; off > 0; off >>= 1) s += __shfl_down(s, off);
  if (lane == 0) t[bl] = s;
}

// ---------------------------------------------------------------------------
// Mention pooling -> X (fp32) + Xb (bf16 shadow for MFMA GEMMs)
// ---------------------------------------------------------------------------
__global__ __launch_bounds__(256) void pool_kernel(const float* __restrict__ lhs,
                                                   const int* __restrict__ pos,
                                                   const int* __restrict__ msk,
                                                   const float* __restrict__ t,
                                                   float* __restrict__ X,
                                                   bf16* __restrict__ Xb) {
  __shared__ float wgt[LSEQ];
  __shared__ int ok[LSEQ];
  const int bm = blockIdx.x;
  const int b = bm >> 7;
  const int tid = threadIdx.x;
  if (tid < LSEQ) ok[tid] = (pos[(size_t)bm * LSEQ + tid] != -1) ? 1 : 0;
  __syncthreads();
  if (tid == 0) {
    const int mk = (msk[bm] != 0) ? 1 : 0;
    int run = 1;
    float lg[LSEQ];
    int vld[LSEQ];
#pragma unroll
    for (int l = 0; l < LSEQ; ++l) {
      run &= ok[l];
      vld[l] = mk & run;
      lg[l] = vld[l] ? t[b * LSEQ + l] : 0.f;
    }
    float mx = lg[0];
#pragma unroll
    for (int l = 1; l < LSEQ; ++l) mx = fmaxf(mx, lg[l]);
    float s = 0.f;
#pragma unroll
    for (int l = 0; l < LSEQ; ++l) { lg[l] = expf(lg[l] - mx); s += lg[l]; }
    const float inv = 1.f / s;
#pragma unroll
    for (int l = 0; l < LSEQ; ++l) wgt[l] = vld[l] ? lg[l] * inv : 0.f;
  }
  __syncthreads();
#pragma unroll
  for (int u = 0; u < 3; ++u) {
    const int d = tid + 256 * u;
    float acc = 0.f;
#pragma unroll
    for (int l = 0; l < LSEQ; ++l)
      acc += wgt[l] * lhs[((size_t)b * SSEQ + l) * DD + d];
    X[(size_t)bm * DD + d] = acc;
    Xb[(size_t)bm * DD + d] = (bf16)acc;
  }
}

// ---------------------------------------------------------------------------
// MFMA GEMM (m97 structure): C[M,N] = A[M,K](bf16) * B[N,K](bf16)^T + bias
// 128x128 tile, BK=32, 256 thr = 4 waves (2x2 of 64x64 wave tiles),
// global_load_lds width=16 staging, ds_read_b128 fragments,
// 16x mfma_f32_16x16x32_bf16 per wave per K-step. M, N, K multiples of
// 128/128/32 (callers pad weights); only the store/bias path is N-guarded.
// ---------------------------------------------------------------------------
template <int OUT_BF16, int RELU, int HAS_BIAS, int GUARD_N>
__global__ __launch_bounds__(256) void gemm_mfma(const bf16* __restrict__ A,
                                                 const bf16* __restrict__ B,
                                                 const float* __restrict__ bias,
                                                 void* __restrict__ Cp,
                                                 int K, int ldc, int ncols) {
  __shared__ __align__(16) bf16 As[128 * 32];
  __shared__ __align__(16) bf16 Bs[128 * 32];
  const int tid = threadIdx.x;
  const int wave = tid >> 6, lane = tid & 63;
  const int rb = blockIdx.y * 128, cb = blockIdx.x * 128;
  const int wm = (wave >> 1) * 64, wn = (wave & 1) * 64;

  // staging: wave w covers rows [w*32, w*32+32); lane -> (row, k) so that
  // LDS element index == wave*1024 + lane*8 (row-major [128][32], no pad)
  const int sr = wave * 32 + (lane >> 2);
  const int sk = (lane & 3) * 8;
  const bf16* ga0 = A + (size_t)(rb + sr) * K + sk;
  const bf16* ga1 = A + (size_t)(rb + sr + 16) * K + sk;
  const bf16* gb0 = B + (size_t)(cb + sr) * K + sk;
  const bf16* gb1 = B + (size_t)(cb + sr + 16) * K + sk;
  bf16* sa0 = As + wave * 1024;
  bf16* sa1 = As + wave * 1024 + 512;
  bf16* sb0 = Bs + wave * 1024;
  bf16* sb1 = Bs + wave * 1024 + 512;

  // fragment addressing: A[m=lane&15][k=(lane>>4)*8 + j]
  const int fr = lane & 15, fk = (lane >> 4) * 8;

  f32x4 acc[4][4];
#pragma unroll
  for (int i = 0; i < 4; ++i)
#pragma unroll
    for (int j = 0; j < 4; ++j) acc[i][j] = (f32x4)0.f;

  for (int kb = 0; kb < K; kb += 32) {
    gl2lds16(ga0, sa0); gl2lds16(ga1, sa1);
    gl2lds16(gb0, sb0); gl2lds16(gb1, sb1);
    ga0 += 32; ga1 += 32; gb0 += 32; gb1 += 32;
    __syncthreads();   // drains vmcnt (global_load_lds) before LDS reads
    bf16x8 af[4], bfr[4];
#pragma unroll
    for (int i = 0; i < 4; ++i)
      af[i] = *(const bf16x8*)(As + (wm + i * 16 + fr) * 32 + fk);
#pragma unroll
    for (int j = 0; j < 4; ++j)
      bfr[j] = *(const bf16x8*)(Bs + (wn + j * 16 + fr) * 32 + fk);
#pragma unroll
    for (int i = 0; i < 4; ++i)
#pragma unroll
      for (int j = 0; j < 4; ++j)
        acc[i][j] = __builtin_amdgcn_mfma_f32_16x16x32_bf16(af[i], bfr[j],
                                                            acc[i][j], 0, 0, 0);
    __syncthreads();   // protect LDS from next iteration's staging
  }

  // epilogue: C/D layout col=lane&15, row=(lane>>4)*4+reg (m89-verified)
  const int r0 = rb + wm + ((lane >> 4) << 2);
  const int c0 = cb + wn + fr;
#pragma unroll
  for (int i = 0; i < 4; ++i) {
#pragma unroll
    for (int j = 0; j < 4; ++j) {
      const int col = c0 + j * 16;
      if (GUARD_N && col >= ncols) continue;
      const float bv = HAS_BIAS ? bias[col] : 0.f;
#pragma unroll
      for (int r = 0; r < 4; ++r) {
        float v = acc[i][j][r] + bv;
        if (RELU) v = fmaxf(v, 0.f);
        const int row = r0 + i * 16 + r;
        if (OUT_BF16)
          ((bf16*)Cp)[(size_t)row * ldc + col] = (bf16)v;
        else
          ((float*)Cp)[(size_t)row * ldc + col] = v;
      }
    }
  }
}

// ---------------------------------------------------------------------------
// Attention: one block per (b, h). Reads fp32 QKV, writes bf16 AO.
// ---------------------------------------------------------------------------
__global__ __launch_bounds__(256) void attn_kernel(const float* __restrict__ qkv,
                                                   bf16* __restrict__ ao) {
  __shared__ float smem[2 * 64 * 132 + 128 * 132];
  float* Qs = smem;                  // [64][132] k-major
  float* Ks = smem + 64 * 132;       // [64][132]
  float* Ps = smem + 2 * 64 * 132;   // [128][132] c-major
  float* Vs = smem;                  // alias after S built: [128][68]

  const int tid = threadIdx.x;
  const int b = blockIdx.x / NHEAD;
  const int h = blockIdx.x % NHEAD;
  const float* base = qkv + (size_t)b * NMENT * (3 * DD) + h * HDIM;

#pragma unroll
  for (int it = 0; it < 8; ++it) {
    const int idx = tid + it * 256;
    const int m = idx >> 4;
    const int d0 = (idx & 15) * 4;
    const float4 q = *(const float4*)(base + (size_t)m * (3 * DD) + d0);
    const float4 k = *(const float4*)(base + (size_t)m * (3 * DD) + DD + d0);
    Qs[(d0 + 0) * 132 + m] = q.x; Qs[(d0 + 1) * 132 + m] = q.y;
    Qs[(d0 + 2) * 132 + m] = q.z; Qs[(d0 + 3) * 132 + m] = q.w;
    Ks[(d0 + 0) * 132 + m] = k.x; Ks[(d0 + 1) * 132 + m] = k.y;
    Ks[(d0 + 2) * 132 + m] = k.z; Ks[(d0 + 3) * 132 + m] = k.w;
  }
  __syncthreads();

  const int tm = (tid >> 4) * 8;
  const int tn = (tid & 15) * 8;
  {
    float acc[8][8];
#pragma unroll
    for (int i = 0; i < 8; ++i)
#pragma unroll
      for (int j = 0; j < 8; ++j) acc[i][j] = 0.f;
    for (int d = 0; d < HDIM; ++d) {
      float a[8], bv[8];
      *(float4*)&a[0] = *(const float4*)&Qs[d * 132 + tm];
      *(float4*)&a[4] = *(const float4*)&Qs[d * 132 + tm + 4];
      *(float4*)&bv[0] = *(const float4*)&Ks[d * 132 + tn];
      *(float4*)&bv[4] = *(const float4*)&Ks[d * 132 + tn + 4];
#pragma unroll
      for (int i = 0; i < 8; ++i)
#pragma unroll
        for (int j = 0; j < 8; ++j)
          acc[i][j] = fmaf(a[i], bv[j], acc[i][j]);
    }
    const float scale = 0.125f;
#pragma unroll
    for (int i = 0; i < 8; ++i)
#pragma unroll
      for (int j = 0; j < 8; ++j)
        Ps[(tn + j) * 132 + (tm + i)] = acc[i][j] * scale;
  }
  __syncthreads();

#pragma unroll
  for (int it = 0; it < 8; ++it) {
    const int idx = tid + it * 256;
    const int m = idx >> 4;
    const int d0 = (idx & 15) * 4;
    const float4 v = *(const float4*)(base + (size_t)m * (3 * DD) + 2 * DD + d0);
    *(float4*)&Vs[m * 68 + d0] = v;
  }
  if (tid < NMENT) {
    const int r = tid;
    float mx = -1e30f;
    for (int c = 0; c < NMENT; ++c) mx = fmaxf(mx, Ps[c * 132 + r]);
    float s = 0.f;
    for (int c = 0; c < NMENT; ++c) {
      const float e = expf(Ps[c * 132 + r] - mx);
      Ps[c * 132 + r] = e;
      s += e;
    }
    const float inv = 1.f / s;
    for (int c = 0; c < NMENT; ++c) Ps[c * 132 + r] *= inv;
  }
  __syncthreads();

  const int om = (tid >> 4) * 8;
  const int od = (tid & 15) * 4;
  float oacc[8][4];
#pragma unroll
  for (int i = 0; i < 8; ++i)
#pragma unroll
    for (int j = 0; j < 4; ++j) oacc[i][j] = 0.f;
  for (int c = 0; c < NMENT; ++c) {
    float p[8];
    *(float4*)&p[0] = *(const float4*)&Ps[c * 132 + om];
    *(float4*)&p[4] = *(const float4*)&Ps[c * 132 + om + 4];
    const float4 vv = *(const float4*)&Vs[c * 68 + od];
#pragma unroll
    for (int i = 0; i < 8; ++i) {
      oacc[i][0] = fmaf(p[i], vv.x, oacc[i][0]);
      oacc[i][1] = fmaf(p[i], vv.y, oacc[i][1]);
      oacc[i][2] = fmaf(p[i], vv.z, oacc[i][2]);
      oacc[i][3] = fmaf(p[i], vv.w, oacc[i][3]);
    }
  }
#pragma unroll
  for (int i = 0; i < 8; ++i) {
    bf16x4 ov;
    ov.x = (bf16)oacc[i][0]; ov.y = (bf16)oacc[i][1];
    ov.z = (bf16)oacc[i][2]; ov.w = (bf16)oacc[i][3];
    *(bf16x4*)(ao + (size_t)(b * NMENT + om + i) * DD + h * HDIM + od) = ov;
  }
}

// ---------------------------------------------------------------------------
// out = LayerNorm(x + y) * w + b -> fp32 o + bf16 ob
// ---------------------------------------------------------------------------
__global__ __launch_bounds__(256) void ln_kernel(const float* __restrict__ x,
                                                 const float* __restrict__ y,
                                                 const float* __restrict__ w,
                                                 const float* __restrict__ bb,
                                                 float* __restrict__ o,
                                                 bf16* __restrict__ ob) {
  __shared__ float red1[4], red2[4];
  __shared__ float mshare, vshare;
  const int row = blockIdx.x;
  const int tid = threadIdx.x;
  const int wave = tid >> 6, lane = tid & 63;
  const float* xr = x + (size_t)row * DD;
  const float* yr = y + (size_t)row * DD;
  float v[3];
  float s = 0.f;
#pragma unroll
  for (int u = 0; u < 3; ++u) {
    v[u] = xr[tid + 256 * u] + yr[tid + 256 * u];
    s += v[u];
  }
#pragma unroll
  for (int off = 32; off > 0; off >>= 1) s += __shfl_down(s, off);
  if (lane == 0) red1[wave] = s;
  __syncthreads();
  if (tid == 0) mshare = (red1[0] + red1[1] + red1[2] + red1[3]) * (1.f / DD);
  __syncthreads();
  const float mean = mshare;
  float q = 0.f;
#pragma unroll
  for (int u = 0; u < 3; ++u) { const float d = v[u] - mean; q += d * d; }
#pragma unroll
  for (int off = 32; off > 0; off >>= 1) q += __shfl_down(q, off);
  if (lane == 0) red2[wave] = q;
  __syncthreads();
  if (tid == 0)
    vshare = rsqrtf((red2[0] + red2[1] + red2[2] + red2[3]) * (1.f / DD) + 1e-5f);
  __syncthreads();
  const float rstd = vshare;
  float* orow = o + (size_t)row * DD;
  bf16* brow = ob + (size_t)row * DD;
#pragma unroll
  for (int u = 0; u < 3; ++u) {
    const int d = tid + 256 * u;
    const float r = (v[u] - mean) * rstd * w[d] + bb[d];
    orow[d] = r;
    brow[d] = (bf16)r;
  }
}

// ---------------------------------------------------------------------------
extern "C" void kernel_launch(void* const* d_in, const int* in_sizes, int n_in,
                              void* d_out, int out_size, void* d_ws, size_t ws_size,
                              hipStream_t stream) {
  const float* lhs    = (const float*)d_in[0];
  const int*   pos    = (const int*)d_in[1];
  const int*   msk    = (const int*)d_in[2];
  const float* attn_w = (const float*)d_in[3];
  // d_in[4] attn_b cancels in softmax
  const float* qkv_w  = (const float*)d_in[5];
  const float* qkv_b  = (const float*)d_in[6];
  const float* out_w  = (const float*)d_in[7];
  const float* out_b  = (const float*)d_in[8];
  const float* ff1_w  = (const float*)d_in[11];
  const float* ff1_b  = (const float*)d_in[12];
  const float* ff2_w  = (const float*)d_in[13];
  const float* ff2_b  = (const float*)d_in[14];
  const float* ln1_w  = (const float*)d_in[9];
  const float* ln1_b  = (const float*)d_in[10];
  const float* ln2_w  = (const float*)d_in[15];
  const float* ln2_b  = (const float*)d_in[16];
  const float* cls_w1 = (const float*)d_in[17];
  const float* cls_w2 = (const float*)d_in[18];
  const float* cls_b2 = (const float*)d_in[19];
  float* out = (float*)d_out;

  // workspace carve-up (~121 MB total)
  char* p = (char*)d_ws;
  auto carve = [&](size_t bytes) {
    void* r = (void*)p;
    p += (bytes + 255) & ~(size_t)255;
    return r;
  };
  float* T    = (float*)carve(512 * 4);
  float* X    = (float*)carve((size_t)NM * DD * 4);
  float* QKV  = (float*)carve((size_t)NM * 3 * DD * 4);
  float* B3   = (float*)carve((size_t)NM * DD * 4);
  bf16* Xb    = (bf16*)carve((size_t)NM * DD * 2);
  bf16* AOb   = (bf16*)carve((size_t)NM * DD * 2);
  bf16* H1    = (bf16*)carve((size_t)NM * DFF * 2);
  bf16* Hb    = (bf16*)carve((size_t)NM * 128 * 2);
  bf16* Wqkv  = (bf16*)carve((size_t)NLAYER * 3 * DD * DD * 2);
  bf16* Wout  = (bf16*)carve((size_t)NLAYER * DD * DD * 2);
  bf16* Wff1  = (bf16*)carve((size_t)NLAYER * DFF * DD * 2);
  bf16* Wff2  = (bf16*)carve((size_t)NLAYER * DD * DFF * 2);
  bf16* Wc1   = (bf16*)carve((size_t)128 * DD * 2);
  bf16* Wc2   = (bf16*)carve((size_t)50048 * 128 * 2);

  // weight conversions (every launch; ~210 MB traffic ~ 40 us)
  {
    const int n_qkv = NLAYER * 3 * DD * DD / 4;   // 1,769,472
    const int n_out = NLAYER * DD * DD / 4;       //   589,824
    const int n_ff  = NLAYER * DFF * DD / 4;      // 2,359,296
    conv_bf16<<<(n_qkv + 255) / 256, 256, 0, stream>>>(qkv_w, Wqkv, n_qkv);
    conv_bf16<<<(n_out + 255) / 256, 256, 0, stream>>>(out_w, Wout, n_out);
    conv_bf16<<<(n_ff + 255) / 256, 256, 0, stream>>>(ff1_w, Wff1, n_ff);
    conv_bf16<<<(n_ff + 255) / 256, 256, 0, stream>>>(ff2_w, Wff2, n_ff);
    const int t1 = 128 * DD;          // 98,304
    const int t2 = 50048 * 128;       // 6,406,144
    conv_pad<<<(t1 + 255) / 256, 256, 0, stream>>>(cls_w1, Wc1, 100, DD, DD, t1);
    conv_pad<<<(t2 + 255) / 256, 256, 0, stream>>>(cls_w2, Wc2, NENT, 100, 128, t2);
  }

  tdot_kernel<<<NBATCH * LSEQ, 64, 0, stream>>>(lhs, attn_w, T);
  pool_kernel<<<NM, 256, 0, stream>>>(lhs, pos, msk, T, X, Xb);

  for (int i = 0; i < NLAYER; ++i) {
    gemm_mfma<0, 0, 1, 0><<<dim3(18, 16), 256, 0, stream>>>(
        Xb, Wqkv + (size_t)i * 3 * DD * DD, qkv_b + (size_t)i * 3 * DD, QKV,
        DD, 3 * DD, 3 * DD);
    attn_kernel<<<NBATCH * NHEAD, 256, 0, stream>>>(QKV, AOb);
    gemm_mfma<0, 0, 1, 0><<<dim3(6, 16), 256, 0, stream>>>(
        AOb, Wout + (size_t)i * DD * DD, out_b + (size_t)i * DD, B3,
        DD, DD, DD);
    ln_kernel<<<NM, 256, 0, stream>>>(X, B3, ln1_w + (size_t)i * DD,
                                      ln1_b + (size_t)i * DD, X, Xb);
    gemm_mfma<1, 1, 1, 0><<<dim3(24, 16), 256, 0, stream>>>(
        Xb, Wff1 + (size_t)i * DFF * DD, ff1_b + (size_t)i * DFF, H1,
        DD, DFF, DFF);
    gemm_mfma<0, 0, 1, 0><<<dim3(6, 16), 256, 0, stream>>>(
        H1, Wff2 + (size_t)i * DD * DFF, ff2_b + (size_t)i * DD, B3,
        DFF, DD, DD);
    ln_kernel<<<NM, 256, 0, stream>>>(X, B3, ln2_w + (size_t)i * DD,
                                      ln2_b + (size_t)i * DD, X, Xb);
  }

  // classifier: Xb @ Wc1^T -> Hb [2048][128] (cols 100..127 are zeros),
  // then Hb @ Wc2^T + b -> out [2048][50000]
  gemm_mfma<1, 0, 0, 0><<<dim3(1, 16), 256, 0, stream>>>(
      Xb, Wc1, nullptr, Hb, DD, 128, 128);
  gemm_mfma<0, 0, 1, 1><<<dim3(391, 16), 256, 0, stream>>>(
      Hb, Wc2, cls_b2, out, 128, NENT, NENT);
}